// Round 5
// baseline (123.526 us; speedup 1.0000x reference)
//
#include <hip/hip_runtime.h>

// Capsule routing collapses algebraically:
//   c = softmax(b, axis=1)  =>  sum_m c[b,m,i] == 1 exactly
//   o = einsum('bmi,bnid->bnd', c, u_hat) = sum_i u_hat[b,n,i,d]
//   u_hat linear in u  =>  o[b,k] = sum_din (sum_i u[b,i,din]) * W[din,k]
// Single fused kernel: 1024 producer blocks colsum u into P; the last 256
// blocks to arrive (arrival-order >= 768) become GEMM blocks.
// Deadlock-free: a spinner has arrival order o >= 768; if every resident
// block were a spinner, all 1024 increments already happened -> spin exits.

constexpr int B    = 32;
constexpr int I    = 1024;
constexpr int DIN  = 512;
constexpr int K    = 512;            // NUM_CAPSULE * DIM_CAPSULE
constexpr int CHUNKS = 32;
constexpr int ROWS   = I / CHUNKS;   // 32
constexpr int NBLK   = B * CHUNKS;   // 1024
constexpr int NGEMM  = 256;          // 32 b * 8 k-tiles

__global__ __launch_bounds__(256, 4) void fused_kernel(
    const float* __restrict__ u, const float* __restrict__ W,
    float* __restrict__ out, float* __restrict__ P, unsigned* cnt) {
  const int t = threadIdx.x;

  __shared__ float4 Uh[2][DIN / 4];
  __shared__ float  U[DIN];
  __shared__ float  red[4][64];
  __shared__ unsigned ord_s;

  // ---------- Phase 1: colsum of my (b, chunk) slab ----------
  {
    const int b     = blockIdx.x >> 5;
    const int chunk = blockIdx.x & 31;
    const int c4   = t & 127;          // float4 column
    const int rh   = t >> 7;           // row half: 0 or 1
    const float4* src = reinterpret_cast<const float4*>(
        u + ((size_t)b * I + (size_t)chunk * ROWS) * DIN) + c4;
    float4 s = make_float4(0.f, 0.f, 0.f, 0.f);
    #pragma unroll
    for (int r = 0; r < ROWS / 2; ++r) {
      float4 v = src[(size_t)(rh * (ROWS / 2) + r) * (DIN / 4)];
      s.x += v.x; s.y += v.y; s.z += v.z; s.w += v.w;
    }
    Uh[rh][c4] = s;
    __syncthreads();
    if (t < DIN / 4) {
      float4 a = Uh[0][t], c = Uh[1][t];
      float4 r4 = make_float4(a.x + c.x, a.y + c.y, a.z + c.z, a.w + c.w);
      reinterpret_cast<float4*>(P + ((size_t)b * CHUNKS + chunk) * DIN)[t] = r4;
    }
    __syncthreads();
  }

  // ---------- Arrive; last NGEMM arrivals become GEMM blocks ----------
  if (t == 0) {
    __threadfence();  // release P to device scope
    ord_s = __hip_atomic_fetch_add(cnt, 1u, __ATOMIC_ACQ_REL,
                                   __HIP_MEMORY_SCOPE_AGENT);
  }
  __syncthreads();
  const unsigned ord = ord_s;
  if (ord < (unsigned)(NBLK - NGEMM)) return;  // pure producer, done

  if (t == 0) {
    while (__hip_atomic_load(cnt, __ATOMIC_ACQUIRE,
                             __HIP_MEMORY_SCOPE_AGENT) < (unsigned)NBLK) {
      __builtin_amdgcn_s_sleep(2);
    }
  }
  __syncthreads();
  __threadfence();  // acquire: all P visible

  // ---------- Phase 2: GEMM role = ord - 768 ----------
  const int role = (int)ord - (NBLK - NGEMM);   // 0..255
  const int gb   = role >> 3;
  const int k0   = (role & 7) * 64;

  // Stage 1: U[gb][:] = sum_c P[gb][c][:]  (vectorized, coalesced)
  const float4* P4 =
      reinterpret_cast<const float4*>(P + (size_t)gb * CHUNKS * DIN);
  const int col = t & 127, half = t >> 7;
  float4 s = make_float4(0.f, 0.f, 0.f, 0.f);
  #pragma unroll
  for (int c = 0; c < CHUNKS / 2; ++c) {
    float4 v = P4[(size_t)(half * (CHUNKS / 2) + c) * (DIN / 4) + col];
    s.x += v.x; s.y += v.y; s.z += v.z; s.w += v.w;
  }
  __syncthreads();   // Uh reuse: phase-1 readers are done (same block)
  Uh[half][col] = s;
  __syncthreads();
  if (t < DIN / 4) {
    float4 a = Uh[0][t], c4 = Uh[1][t];
    U[4 * t + 0] = a.x + c4.x;
    U[4 * t + 1] = a.y + c4.y;
    U[4 * t + 2] = a.z + c4.z;
    U[4 * t + 3] = a.w + c4.w;
  }
  __syncthreads();

  // Stage 2: wave = one din-group of 128, 64 consecutive W cols.
  const int kk = t & 63;
  const int dg = t >> 6;
  const float* Wp = W + (size_t)(dg * 128) * K + k0 + kk;
  float acc = 0.f;
  #pragma unroll 16
  for (int d = 0; d < 128; ++d)
    acc += U[dg * 128 + d] * Wp[(size_t)d * K];   // U read = wave broadcast
  red[dg][kk] = acc;
  __syncthreads();

  if (t < 64)
    out[(size_t)gb * K + k0 + t] =
        red[0][t] + red[1][t] + red[2][t] + red[3][t];
}

extern "C" void kernel_launch(void* const* d_in, const int* in_sizes, int n_in,
                              void* d_out, int out_size, void* d_ws, size_t ws_size,
                              hipStream_t stream) {
  const float* u = (const float*)d_in[0];   // [32,1024,512] f32
  const float* W = (const float*)d_in[1];   // [1,512,512]   f32
  float* out = (float*)d_out;               // [32,32,16]    f32
  float* P   = (float*)d_ws;                // [32][32][512] f32 = 2 MiB
  unsigned* cnt = (unsigned*)((char*)d_ws + (2u << 20));

  hipMemsetAsync(cnt, 0, sizeof(unsigned), stream);
  fused_kernel<<<NBLK, 256, 0, stream>>>(u, W, out, P, cnt);
}

// Round 6
// 80.408 us; speedup vs baseline: 1.5362x; 1.5362x over previous
//
#include <hip/hip_runtime.h>

// o[b,k] = sum_din (sum_i u[b,i,din]) * W[din,k]  (routing collapses; see r0).
// Single fused kernel, producer->consumer via per-access coherent atomics:
//  - 1024 producer blocks: colsum 32 rows -> P[b][chunk] (sc-flagged stores),
//    manual release (vmcnt drain + barrier), relaxed fetch_add cnt[b].
//  - the 32nd arriver of b reduces P[b] -> U[b], sets flag ub[b].
//  - 32 GEMM blocks hold a 16-col W slice in registers, consume U[b] in order.
// No ACQUIRE/RELEASE orderings anywhere => no buffer_wbl2 / buffer_inv
// (round-5's failure mode). Counters 64B apart. Deterministic FP order.

constexpr int NB   = 32;     // batch
constexpr int I    = 1024;
constexpr int DIN  = 512;
constexpr int K    = 512;
constexpr int CHUNKS = 32;
constexpr int ROWS   = I / CHUNKS;        // 32
constexpr int NPROD  = NB * CHUNKS;       // 1024
constexpr int NGEMM  = 32;                // 16-col k-tiles
constexpr int NBLK   = NPROD + NGEMM;

#define SCOPE __HIP_MEMORY_SCOPE_AGENT

__global__ __launch_bounds__(128) void fused_kernel(
    const float* __restrict__ u, const float* __restrict__ W,
    float* __restrict__ out, float* __restrict__ U,
    unsigned* __restrict__ cnt, unsigned* __restrict__ ub,
    float* __restrict__ P) {
  const int t = threadIdx.x;
  __shared__ unsigned ord_s;
  __shared__ float Ut[DIN];
  __shared__ float red[128];

  if (blockIdx.x < NPROD) {
    // ---------------- producer: colsum of (b, chunk) slab ----------------
    const int b = blockIdx.x >> 5, chunk = blockIdx.x & 31;
    const float4* src = reinterpret_cast<const float4*>(
        u + ((size_t)b * I + (size_t)chunk * ROWS) * DIN) + t;
    float4 s = make_float4(0.f, 0.f, 0.f, 0.f);
    #pragma unroll
    for (int r = 0; r < ROWS; ++r) {
      float4 v = src[(size_t)r * (DIN / 4)];
      s.x += v.x; s.y += v.y; s.z += v.z; s.w += v.w;
    }
    float* Pp = P + ((size_t)b * CHUNKS + chunk) * DIN + 4 * t;
    __hip_atomic_store(Pp + 0, s.x, __ATOMIC_RELAXED, SCOPE);
    __hip_atomic_store(Pp + 1, s.y, __ATOMIC_RELAXED, SCOPE);
    __hip_atomic_store(Pp + 2, s.z, __ATOMIC_RELAXED, SCOPE);
    __hip_atomic_store(Pp + 3, s.w, __ATOMIC_RELAXED, SCOPE);
    asm volatile("s_waitcnt vmcnt(0)" ::: "memory");  // my stores performed
    __syncthreads();                                  // all 128 threads' too
    if (t == 0)
      ord_s = __hip_atomic_fetch_add(&cnt[b * 16], 1u, __ATOMIC_RELAXED, SCOPE);
    __syncthreads();
    if (ord_s != (unsigned)(CHUNKS - 1)) return;

    // ---- last arriver of b: P[b] -> U[b] (all 32 chunks' stores visible) ----
    float a0 = 0.f, a1 = 0.f, a2 = 0.f, a3 = 0.f;
    const float* Pb = P + (size_t)b * CHUNKS * DIN + 4 * t;
    #pragma unroll 8
    for (int c = 0; c < CHUNKS; ++c) {
      const float* q = Pb + (size_t)c * DIN;
      a0 += __hip_atomic_load(q + 0, __ATOMIC_RELAXED, SCOPE);
      a1 += __hip_atomic_load(q + 1, __ATOMIC_RELAXED, SCOPE);
      a2 += __hip_atomic_load(q + 2, __ATOMIC_RELAXED, SCOPE);
      a3 += __hip_atomic_load(q + 3, __ATOMIC_RELAXED, SCOPE);
    }
    float* Up = U + (size_t)b * DIN + 4 * t;
    __hip_atomic_store(Up + 0, a0, __ATOMIC_RELAXED, SCOPE);
    __hip_atomic_store(Up + 1, a1, __ATOMIC_RELAXED, SCOPE);
    __hip_atomic_store(Up + 2, a2, __ATOMIC_RELAXED, SCOPE);
    __hip_atomic_store(Up + 3, a3, __ATOMIC_RELAXED, SCOPE);
    asm volatile("s_waitcnt vmcnt(0)" ::: "memory");
    __syncthreads();
    if (t == 0)
      __hip_atomic_store(&ub[b * 16], 1u, __ATOMIC_RELAXED, SCOPE);
    return;
  }

  // ---------------- consumer: 16-col GEMM tile, W held in registers ----------
  const int g  = blockIdx.x - NPROD;       // 0..31 -> cols [g*16, g*16+16)
  const int kk = t & 15;
  const int dg = t >> 4;                   // 0..7 -> dins [dg*64, dg*64+64)
  const float* Wp = W + (size_t)(dg * 64) * K + g * 16 + kk;
  float w[64];
  #pragma unroll
  for (int d = 0; d < 64; ++d) w[d] = Wp[(size_t)d * K];  // plain: W read-only

  for (int b = 0; b < NB; ++b) {
    if (t == 0) {
      while (__hip_atomic_load(&ub[b * 16], __ATOMIC_RELAXED, SCOPE) == 0u)
        __builtin_amdgcn_s_sleep(8);
    }
    __syncthreads();
    asm volatile("" ::: "memory");
    #pragma unroll
    for (int i = 0; i < 4; ++i)
      Ut[t + 128 * i] = __hip_atomic_load(U + (size_t)b * DIN + t + 128 * i,
                                          __ATOMIC_RELAXED, SCOPE);
    __syncthreads();
    float acc = 0.f;
    #pragma unroll
    for (int d = 0; d < 64; ++d) acc += Ut[dg * 64 + d] * w[d];
    red[t] = acc;
    __syncthreads();
    if (t < 16) {
      float r = 0.f;
      #pragma unroll
      for (int j = 0; j < 8; ++j) r += red[t + 16 * j];
      out[(size_t)b * K + g * 16 + t] = r;
    }
  }
}

extern "C" void kernel_launch(void* const* d_in, const int* in_sizes, int n_in,
                              void* d_out, int out_size, void* d_ws, size_t ws_size,
                              hipStream_t stream) {
  const float* u = (const float*)d_in[0];   // [32,1024,512] f32
  const float* W = (const float*)d_in[1];   // [1,512,512]   f32
  float* out = (float*)d_out;               // [32,32,16]    f32
  char* ws = (char*)d_ws;
  float*    U   = (float*)ws;                        // 64 KB
  unsigned* cnt = (unsigned*)(ws + 65536);           // 32 ctrs, 64B apart (2KB)
  unsigned* ub  = (unsigned*)(ws + 65536 + 2048);    // 32 flags, 64B apart (2KB)
  float*    P   = (float*)(ws + 65536 + 4096);       // 2 MB

  hipMemsetAsync(ws + 65536, 0, 4096, stream);       // zero cnt + ub
  fused_kernel<<<NBLK, 128, 0, stream>>>(u, W, out, U, cnt, ub, P);
}

// Round 7
// 26.079 us; speedup vs baseline: 4.7366x; 3.0833x over previous
//
#include <hip/hip_runtime.h>

// DIAGNOSTIC ROUND. Output is bit-identical to round-3 (best, 23.4 us).
// Kernel A reads u 3x: pass 1 -> P (exact r3 semantics); passes 2-3 feed a
// dummy accumulator kept live via asm (no DCE), separated by memory clobbers
// (no CSE). This makes A a ~50us dispatch so it finally lands in the top-5
// rocprof rows and we see its hbm_gbps / FETCH_SIZE / VALUBusy / Occupancy.

constexpr int B    = 32;
constexpr int I    = 1024;
constexpr int DIN  = 512;
constexpr int K    = 512;
constexpr int CHUNKS = 32;
constexpr int ROWS   = I / CHUNKS;   // 32

__global__ __launch_bounds__(128) void colsum_diag_kernel(
    const float* __restrict__ u, float* __restrict__ P) {
  const int b     = blockIdx.x >> 5;
  const int chunk = blockIdx.x & 31;
  const int t     = threadIdx.x;
  const float4* src = reinterpret_cast<const float4*>(
      u + ((size_t)b * I + (size_t)chunk * ROWS) * DIN) + t;

  // Pass 1 — the real colsum (identical to round 3).
  float4 s = make_float4(0.f, 0.f, 0.f, 0.f);
  #pragma unroll
  for (int r = 0; r < ROWS; ++r) {
    float4 v = src[(size_t)r * (DIN / 4)];
    s.x += v.x; s.y += v.y; s.z += v.z; s.w += v.w;
  }

  // Passes 2,3 — diagnostic re-reads. memory clobber forces re-load (no CSE);
  // final asm keeps d live (no DCE, guide rule #17).
  float4 d = make_float4(0.f, 0.f, 0.f, 0.f);
  #pragma unroll 1
  for (int pass = 0; pass < 2; ++pass) {
    asm volatile("" ::: "memory");
    #pragma unroll
    for (int r = 0; r < ROWS; ++r) {
      float4 v = src[(size_t)r * (DIN / 4)];
      d.x += v.x; d.y += v.y; d.z += v.z; d.w += v.w;
    }
  }
  asm volatile("" :: "v"(d.x), "v"(d.y), "v"(d.z), "v"(d.w));

  reinterpret_cast<float4*>(P + ((size_t)b * CHUNKS + chunk) * DIN)[t] = s;
}

// Kernel B — verbatim round-3 lean version.
__global__ __launch_bounds__(256) void gemm_kernel(
    const float* __restrict__ P, const float* __restrict__ W,
    float* __restrict__ out) {
  const int b  = blockIdx.x >> 3;
  const int k0 = (blockIdx.x & 7) * 64;
  const int t  = threadIdx.x;

  __shared__ float  U[DIN];
  __shared__ float4 Uh[2][DIN / 4];
  __shared__ float  red[4][64];

  const float4* P4 = reinterpret_cast<const float4*>(P + (size_t)b * CHUNKS * DIN);
  const int col = t & 127, half = t >> 7;
  float4 s = make_float4(0.f, 0.f, 0.f, 0.f);
  #pragma unroll
  for (int c = 0; c < CHUNKS / 2; ++c) {
    float4 v = P4[(size_t)(half * (CHUNKS / 2) + c) * (DIN / 4) + col];
    s.x += v.x; s.y += v.y; s.z += v.z; s.w += v.w;
  }
  Uh[half][col] = s;
  __syncthreads();
  if (t < DIN / 4) {
    float4 a = Uh[0][t], c4 = Uh[1][t];
    U[4 * t + 0] = a.x + c4.x;
    U[4 * t + 1] = a.y + c4.y;
    U[4 * t + 2] = a.z + c4.z;
    U[4 * t + 3] = a.w + c4.w;
  }
  __syncthreads();

  const int kk = t & 63;
  const int dg = t >> 6;
  const float* Wp = W + (size_t)(dg * 128) * K + k0 + kk;
  float acc = 0.f;
  #pragma unroll 16
  for (int d = 0; d < 128; ++d)
    acc += U[dg * 128 + d] * Wp[(size_t)d * K];
  red[dg][kk] = acc;
  __syncthreads();

  if (t < 64)
    out[(size_t)b * K + k0 + t] =
        red[0][t] + red[1][t] + red[2][t] + red[3][t];
}

extern "C" void kernel_launch(void* const* d_in, const int* in_sizes, int n_in,
                              void* d_out, int out_size, void* d_ws, size_t ws_size,
                              hipStream_t stream) {
  const float* u = (const float*)d_in[0];   // [32,1024,512] f32
  const float* W = (const float*)d_in[1];   // [1,512,512]   f32
  float* out = (float*)d_out;               // [32,32,16]    f32
  float* P   = (float*)d_ws;                // [32][32][512] f32 = 2 MiB

  colsum_diag_kernel<<<B * CHUNKS, 128, 0, stream>>>(u, P);
  gemm_kernel<<<B * 8, 256, 0, stream>>>(P, W, out);
}

// Round 8
// 22.526 us; speedup vs baseline: 5.4837x; 1.1577x over previous
//
#include <hip/hip_runtime.h>

// o[b,k] = sum_din (sum_i u[b,i,din]) * W[din,k]  (routing collapses; see r0).
// Two kernels (fusion abandoned: r5/r6 showed cross-block hand-off is 3-6x
// slower on non-coherent-L2 hardware).
// Round-8 experiment: halve the concurrent DRAM stream count in A
// (512 blocks x 128-KB slabs instead of 1024 x 64-KB), same 8 waves/CU.
// Side benefit: P is 1 MiB, so B's 8x-redundant stage-1 read halves.

constexpr int B    = 32;
constexpr int I    = 1024;
constexpr int DIN  = 512;
constexpr int K    = 512;            // NUM_CAPSULE * DIM_CAPSULE
constexpr int CHUNKS = 16;           // 512 blocks, 128-KB slabs
constexpr int ROWS   = I / CHUNKS;   // 64 rows per chunk

// Kernel A: P[b][chunk][din] = sum_{r in chunk} u[b][chunk*ROWS + r][din]
// 256 threads: row-parity p = t>>7, float4-col c4 = t&127.
// Per iteration the block reads 2 full rows = 4 KB contiguous.
__global__ __launch_bounds__(256) void colsum_kernel(
    const float* __restrict__ u, float* __restrict__ P) {
  const int b     = blockIdx.x >> 4;   // / CHUNKS
  const int chunk = blockIdx.x & 15;   // % CHUNKS
  const int t     = threadIdx.x;       // 0..255
  const int p     = t >> 7;            // row parity
  const int c4    = t & 127;           // float4 column

  __shared__ float4 Uh[2][DIN / 4];

  const float4* src = reinterpret_cast<const float4*>(
      u + ((size_t)b * I + (size_t)chunk * ROWS) * DIN) +
      (size_t)p * (DIN / 4) + c4;
  float4 s = make_float4(0.f, 0.f, 0.f, 0.f);
  #pragma unroll
  for (int k = 0; k < ROWS / 2; ++k) {           // 32 iters, stride 2 rows
    float4 v = src[(size_t)k * (DIN / 2)];       // 2 rows = 256 float4s
    s.x += v.x; s.y += v.y; s.z += v.z; s.w += v.w;
  }
  Uh[p][c4] = s;
  __syncthreads();
  if (t < DIN / 4) {
    float4 a = Uh[0][t], c = Uh[1][t];
    float4 r4 = make_float4(a.x + c.x, a.y + c.y, a.z + c.z, a.w + c.w);
    reinterpret_cast<float4*>(P + ((size_t)b * CHUNKS + chunk) * DIN)[t] = r4;
  }
}

// Kernel B (r3 lean, CHUNKS=16): U[b] = sum_c P[b][c]; out = U * W.
// grid = B*8 blocks (64-wide k-tiles), 256 threads.
__global__ __launch_bounds__(256) void gemm_kernel(
    const float* __restrict__ P, const float* __restrict__ W,
    float* __restrict__ out) {
  const int b  = blockIdx.x >> 3;
  const int k0 = (blockIdx.x & 7) * 64;
  const int t  = threadIdx.x;

  __shared__ float  U[DIN];
  __shared__ float4 Uh[2][DIN / 4];
  __shared__ float  red[4][64];

  // Stage 1: P[b] viewed as [CHUNKS][128] float4. col = t&127, half = t>>7.
  const float4* P4 = reinterpret_cast<const float4*>(P + (size_t)b * CHUNKS * DIN);
  const int col = t & 127, half = t >> 7;
  float4 s = make_float4(0.f, 0.f, 0.f, 0.f);
  #pragma unroll
  for (int c = 0; c < CHUNKS / 2; ++c) {
    float4 v = P4[(size_t)(half * (CHUNKS / 2) + c) * (DIN / 4) + col];
    s.x += v.x; s.y += v.y; s.z += v.z; s.w += v.w;
  }
  Uh[half][col] = s;
  __syncthreads();
  if (t < DIN / 4) {
    float4 a = Uh[0][t], c4 = Uh[1][t];
    U[4 * t + 0] = a.x + c4.x;
    U[4 * t + 1] = a.y + c4.y;
    U[4 * t + 2] = a.z + c4.z;
    U[4 * t + 3] = a.w + c4.w;
  }
  __syncthreads();

  // Stage 2: wave = one din-group of 128, 64 consecutive W cols; deep unroll
  // keeps ~16 independent W loads in flight.
  const int kk = t & 63;
  const int dg = t >> 6;
  const float* Wp = W + (size_t)(dg * 128) * K + k0 + kk;
  float acc = 0.f;
  #pragma unroll 16
  for (int d = 0; d < 128; ++d)
    acc += U[dg * 128 + d] * Wp[(size_t)d * K];   // U read = wave broadcast
  red[dg][kk] = acc;
  __syncthreads();

  if (t < 64)
    out[(size_t)b * K + k0 + t] =
        red[0][t] + red[1][t] + red[2][t] + red[3][t];
}

extern "C" void kernel_launch(void* const* d_in, const int* in_sizes, int n_in,
                              void* d_out, int out_size, void* d_ws, size_t ws_size,
                              hipStream_t stream) {
  const float* u = (const float*)d_in[0];   // [32,1024,512] f32
  const float* W = (const float*)d_in[1];   // [1,512,512]   f32
  float* out = (float*)d_out;               // [32,32,16]    f32
  float* P   = (float*)d_ws;                // [32][16][512] f32 = 1 MiB

  colsum_kernel<<<B * CHUNKS, 256, 0, stream>>>(u, P);
  gemm_kernel<<<B * 8, 256, 0, stream>>>(P, W, out);
}

// Round 9
// 20.273 us; speedup vs baseline: 6.0931x; 1.1111x over previous
//
#include <hip/hip_runtime.h>

// o[b,k] = sum_din (sum_i u[b,i,din]) * W[din,k]  (routing collapses; see r0).
// Round-9 experiment: non-temporal loads for u. The harness's 256-MiB 0xAA
// ws-fills between replays leave the 256-MiB memory-side L3 full of DIRTY
// lines; a cached streaming read of u then pays ~1 writeback per fill
// (64 MiB read + ~64 MiB eviction writeback ~= the 2x traffic that matches
// A's measured 18 us). nt loads bypass allocation -> no evictions.

typedef float f4 __attribute__((ext_vector_type(4)));

constexpr int B    = 32;
constexpr int I    = 1024;
constexpr int DIN  = 512;
constexpr int K    = 512;            // NUM_CAPSULE * DIM_CAPSULE
constexpr int CHUNKS = 16;           // 512 blocks, 128-KB slabs (r8 best)
constexpr int ROWS   = I / CHUNKS;   // 64 rows per chunk

// Kernel A: P[b][chunk][din] = sum_{r in chunk} u[b][chunk*ROWS + r][din]
// 256 threads: row-parity p = t>>7, float4-col c4 = t&127. nt loads.
__global__ __launch_bounds__(256) void colsum_kernel(
    const float* __restrict__ u, float* __restrict__ P) {
  const int b     = blockIdx.x >> 4;   // / CHUNKS
  const int chunk = blockIdx.x & 15;   // % CHUNKS
  const int t     = threadIdx.x;       // 0..255
  const int p     = t >> 7;            // row parity
  const int c4    = t & 127;           // float4 column

  __shared__ f4 Uh[2][DIN / 4];

  const f4* src = reinterpret_cast<const f4*>(
      u + ((size_t)b * I + (size_t)chunk * ROWS) * DIN) +
      (size_t)p * (DIN / 4) + c4;
  f4 s = (f4)(0.f);
  #pragma unroll
  for (int k = 0; k < ROWS / 2; ++k) {           // 32 iters, stride 2 rows
    f4 v = __builtin_nontemporal_load(src + (size_t)k * (DIN / 2));
    s += v;
  }
  Uh[p][c4] = s;
  __syncthreads();
  if (t < DIN / 4) {
    f4 r4 = Uh[0][t] + Uh[1][t];
    reinterpret_cast<f4*>(P + ((size_t)b * CHUNKS + chunk) * DIN)[t] = r4;
  }
}

// Kernel B (r8 lean): U[b] = sum_c P[b][c]; out = U * W.
// grid = B*8 blocks (64-wide k-tiles), 256 threads.
__global__ __launch_bounds__(256) void gemm_kernel(
    const float* __restrict__ P, const float* __restrict__ W,
    float* __restrict__ out) {
  const int b  = blockIdx.x >> 3;
  const int k0 = (blockIdx.x & 7) * 64;
  const int t  = threadIdx.x;

  __shared__ float  U[DIN];
  __shared__ f4     Uh[2][DIN / 4];
  __shared__ float  red[4][64];

  // Stage 1: P[b] viewed as [CHUNKS][128] f4. col = t&127, half = t>>7.
  const f4* P4 = reinterpret_cast<const f4*>(P + (size_t)b * CHUNKS * DIN);
  const int col = t & 127, half = t >> 7;
  f4 s = (f4)(0.f);
  #pragma unroll
  for (int c = 0; c < CHUNKS / 2; ++c)
    s += P4[(size_t)(half * (CHUNKS / 2) + c) * (DIN / 4) + col];
  Uh[half][col] = s;
  __syncthreads();
  if (t < DIN / 4) {
    f4 a = Uh[0][t] + Uh[1][t];
    U[4 * t + 0] = a.x;
    U[4 * t + 1] = a.y;
    U[4 * t + 2] = a.z;
    U[4 * t + 3] = a.w;
  }
  __syncthreads();

  // Stage 2: wave = one din-group of 128, 64 consecutive W cols; deep unroll
  // keeps ~16 independent W loads in flight.
  const int kk = t & 63;
  const int dg = t >> 6;
  const float* Wp = W + (size_t)(dg * 128) * K + k0 + kk;
  float acc = 0.f;
  #pragma unroll 16
  for (int d = 0; d < 128; ++d)
    acc += U[dg * 128 + d] * Wp[(size_t)d * K];   // U read = wave broadcast
  red[dg][kk] = acc;
  __syncthreads();

  if (t < 64)
    out[(size_t)b * K + k0 + t] =
        red[0][t] + red[1][t] + red[2][t] + red[3][t];
}

extern "C" void kernel_launch(void* const* d_in, const int* in_sizes, int n_in,
                              void* d_out, int out_size, void* d_ws, size_t ws_size,
                              hipStream_t stream) {
  const float* u = (const float*)d_in[0];   // [32,1024,512] f32
  const float* W = (const float*)d_in[1];   // [1,512,512]   f32
  float* out = (float*)d_out;               // [32,32,16]    f32
  float* P   = (float*)d_ws;                // [32][16][512] f32 = 1 MiB

  colsum_kernel<<<B * CHUNKS, 256, 0, stream>>>(u, P);
  gemm_kernel<<<B * 8, 256, 0, stream>>>(P, W, out);
}

// Round 10
// 20.184 us; speedup vs baseline: 6.1199x; 1.0044x over previous
//
#include <hip/hip_runtime.h>

// o[b,k] = sum_din (sum_i u[b,i,din]) * W[din,k]  (routing collapses; see r0).
// r9: nt loads for u (-2.25us; L3 dirty-eviction partially confirmed).
// r10 experiment: 16 waves/CU in A (512 threads/block). In the nt regime
// every load pays ~900cy HBM latency; the r2/r4 occupancy nulls were
// measured in the CACHED regime and don't transfer (rule #23).

typedef float f4 __attribute__((ext_vector_type(4)));

constexpr int B    = 32;
constexpr int I    = 1024;
constexpr int DIN  = 512;
constexpr int K    = 512;            // NUM_CAPSULE * DIM_CAPSULE
constexpr int CHUNKS = 16;           // 512 blocks, 128-KB slabs
constexpr int ROWS   = I / CHUNKS;   // 64 rows per chunk

// Kernel A: P[b][chunk][din] = sum_{r in chunk} u[b][chunk*ROWS + r][din]
// 512 threads: row-slot p = t>>7 (0..3), float4-col c4 = t&127.
// 16 nt float4 loads per thread, fully unrolled; block reads 4 rows/iter.
__global__ __launch_bounds__(512) void colsum_kernel(
    const float* __restrict__ u, float* __restrict__ P) {
  const int b     = blockIdx.x >> 4;   // / CHUNKS
  const int chunk = blockIdx.x & 15;   // % CHUNKS
  const int t     = threadIdx.x;       // 0..511
  const int p     = t >> 7;            // row slot 0..3
  const int c4    = t & 127;           // float4 column

  __shared__ f4 Uh[4][DIN / 4];

  const f4* src = reinterpret_cast<const f4*>(
      u + ((size_t)b * I + (size_t)chunk * ROWS) * DIN) +
      (size_t)p * (DIN / 4) + c4;
  f4 s = (f4)(0.f);
  #pragma unroll
  for (int k = 0; k < ROWS / 4; ++k) {           // 16 iters, stride 4 rows
    f4 v = __builtin_nontemporal_load(src + (size_t)k * DIN);  // 4*(DIN/4)
    s += v;
  }
  Uh[p][c4] = s;
  __syncthreads();
  if (t < DIN / 4) {
    f4 r4 = (Uh[0][t] + Uh[1][t]) + (Uh[2][t] + Uh[3][t]);
    reinterpret_cast<f4*>(P + ((size_t)b * CHUNKS + chunk) * DIN)[t] = r4;
  }
}

// Kernel B (verbatim r9): U[b] = sum_c P[b][c]; out = U * W.
// grid = B*8 blocks (64-wide k-tiles), 256 threads.
__global__ __launch_bounds__(256) void gemm_kernel(
    const float* __restrict__ P, const float* __restrict__ W,
    float* __restrict__ out) {
  const int b  = blockIdx.x >> 3;
  const int k0 = (blockIdx.x & 7) * 64;
  const int t  = threadIdx.x;

  __shared__ float  U[DIN];
  __shared__ f4     Uh[2][DIN / 4];
  __shared__ float  red[4][64];

  const f4* P4 = reinterpret_cast<const f4*>(P + (size_t)b * CHUNKS * DIN);
  const int col = t & 127, half = t >> 7;
  f4 s = (f4)(0.f);
  #pragma unroll
  for (int c = 0; c < CHUNKS / 2; ++c)
    s += P4[(size_t)(half * (CHUNKS / 2) + c) * (DIN / 4) + col];
  Uh[half][col] = s;
  __syncthreads();
  if (t < DIN / 4) {
    f4 a = Uh[0][t] + Uh[1][t];
    U[4 * t + 0] = a.x;
    U[4 * t + 1] = a.y;
    U[4 * t + 2] = a.z;
    U[4 * t + 3] = a.w;
  }
  __syncthreads();

  const int kk = t & 63;
  const int dg = t >> 6;
  const float* Wp = W + (size_t)(dg * 128) * K + k0 + kk;
  float acc = 0.f;
  #pragma unroll 16
  for (int d = 0; d < 128; ++d)
    acc += U[dg * 128 + d] * Wp[(size_t)d * K];   // U read = wave broadcast
  red[dg][kk] = acc;
  __syncthreads();

  if (t < 64)
    out[(size_t)b * K + k0 + t] =
        red[0][t] + red[1][t] + red[2][t] + red[3][t];
}

extern "C" void kernel_launch(void* const* d_in, const int* in_sizes, int n_in,
                              void* d_out, int out_size, void* d_ws, size_t ws_size,
                              hipStream_t stream) {
  const float* u = (const float*)d_in[0];   // [32,1024,512] f32
  const float* W = (const float*)d_in[1];   // [1,512,512]   f32
  float* out = (float*)d_out;               // [32,32,16]    f32
  float* P   = (float*)d_ws;                // [32][16][512] f32 = 1 MiB

  colsum_kernel<<<B * CHUNKS, 512, 0, stream>>>(u, P);
  gemm_kernel<<<B * 8, 256, 0, stream>>>(P, W, out);
}

// Round 11
// 20.013 us; speedup vs baseline: 6.1722x; 1.0086x over previous
//
#include <hip/hip_runtime.h>
#include <stdint.h>

// o[b,k] = sum_din (sum_i u[b,i,din]) * W[din,k]  (routing collapses; see r0).
// r9: nt loads -2.25us (dirty-L3 eviction partially confirmed).
// r10: 16 waves/CU null -> latency/occupancy ruled out.
// r11 experiment: nt ALONE is an evict-first HINT; the line may still
// ALLOCATE in L3, still evicting one dirty 0xAA ws line (-> HBM writeback)
// per 128B fetched. sc1+nt (system-scope non-temporal) requests no-allocate.
// Only inline asm can emit sc1. Loads of never-written u: scope bits are
// correctness-free. FP summation order identical to r10.

typedef float f4 __attribute__((ext_vector_type(4)));

constexpr int B    = 32;
constexpr int I    = 1024;
constexpr int DIN  = 512;
constexpr int K    = 512;            // NUM_CAPSULE * DIM_CAPSULE
constexpr int CHUNKS = 16;           // 512 blocks, 128-KB slabs
constexpr int ROWS   = I / CHUNKS;   // 64 rows per chunk

// Kernel A: P[b][chunk][din] = sum_{r in chunk} u[b][chunk*ROWS + r][din]
// 512 threads: row-slot p = t>>7 (0..3), f4-col c4 = t&127.
// 16 sc1-nt dwordx4 loads issued back-to-back from one asm block
// (single vmcnt(0) at the end of the same block -> no hoist hazard).
__global__ __launch_bounds__(512) void colsum_kernel(
    const float* __restrict__ u, float* __restrict__ P) {
  const int b     = blockIdx.x >> 4;   // / CHUNKS
  const int chunk = blockIdx.x & 15;   // % CHUNKS
  const int t     = threadIdx.x;       // 0..511
  const int p     = t >> 7;            // row slot 0..3
  const int c4    = t & 127;           // f4 column

  __shared__ f4 Uh[4][DIN / 4];

  const float* base =
      u + ((size_t)b * I + (size_t)chunk * ROWS + p) * DIN + 4 * (size_t)c4;
  uint64_t a  = (uint64_t)base;
  uint64_t st = 4ull * DIN * sizeof(float);   // 4 rows = 8192 B per step

  f4 d0, d1, d2, d3, d4, d5, d6, d7, d8, d9, d10, d11, d12, d13, d14, d15;
  asm volatile(
      "global_load_dwordx4 %[d0],  %[a], off sc1 nt\n\t"
      "v_lshl_add_u64 %[a], %[st], 0, %[a]\n\t"
      "global_load_dwordx4 %[d1],  %[a], off sc1 nt\n\t"
      "v_lshl_add_u64 %[a], %[st], 0, %[a]\n\t"
      "global_load_dwordx4 %[d2],  %[a], off sc1 nt\n\t"
      "v_lshl_add_u64 %[a], %[st], 0, %[a]\n\t"
      "global_load_dwordx4 %[d3],  %[a], off sc1 nt\n\t"
      "v_lshl_add_u64 %[a], %[st], 0, %[a]\n\t"
      "global_load_dwordx4 %[d4],  %[a], off sc1 nt\n\t"
      "v_lshl_add_u64 %[a], %[st], 0, %[a]\n\t"
      "global_load_dwordx4 %[d5],  %[a], off sc1 nt\n\t"
      "v_lshl_add_u64 %[a], %[st], 0, %[a]\n\t"
      "global_load_dwordx4 %[d6],  %[a], off sc1 nt\n\t"
      "v_lshl_add_u64 %[a], %[st], 0, %[a]\n\t"
      "global_load_dwordx4 %[d7],  %[a], off sc1 nt\n\t"
      "v_lshl_add_u64 %[a], %[st], 0, %[a]\n\t"
      "global_load_dwordx4 %[d8],  %[a], off sc1 nt\n\t"
      "v_lshl_add_u64 %[a], %[st], 0, %[a]\n\t"
      "global_load_dwordx4 %[d9],  %[a], off sc1 nt\n\t"
      "v_lshl_add_u64 %[a], %[st], 0, %[a]\n\t"
      "global_load_dwordx4 %[d10], %[a], off sc1 nt\n\t"
      "v_lshl_add_u64 %[a], %[st], 0, %[a]\n\t"
      "global_load_dwordx4 %[d11], %[a], off sc1 nt\n\t"
      "v_lshl_add_u64 %[a], %[st], 0, %[a]\n\t"
      "global_load_dwordx4 %[d12], %[a], off sc1 nt\n\t"
      "v_lshl_add_u64 %[a], %[st], 0, %[a]\n\t"
      "global_load_dwordx4 %[d13], %[a], off sc1 nt\n\t"
      "v_lshl_add_u64 %[a], %[st], 0, %[a]\n\t"
      "global_load_dwordx4 %[d14], %[a], off sc1 nt\n\t"
      "v_lshl_add_u64 %[a], %[st], 0, %[a]\n\t"
      "global_load_dwordx4 %[d15], %[a], off sc1 nt\n\t"
      "s_waitcnt vmcnt(0)"
      : [d0] "=&v"(d0), [d1] "=&v"(d1), [d2] "=&v"(d2), [d3] "=&v"(d3),
        [d4] "=&v"(d4), [d5] "=&v"(d5), [d6] "=&v"(d6), [d7] "=&v"(d7),
        [d8] "=&v"(d8), [d9] "=&v"(d9), [d10] "=&v"(d10), [d11] "=&v"(d11),
        [d12] "=&v"(d12), [d13] "=&v"(d13), [d14] "=&v"(d14),
        [d15] "=&v"(d15), [a] "+v"(a)
      : [st] "v"(st)
      : "memory");

  // Same left-assoc order as r10's sequential loop (bit-identical output).
  f4 s = d0;
  s += d1;  s += d2;  s += d3;  s += d4;  s += d5;  s += d6;  s += d7;
  s += d8;  s += d9;  s += d10; s += d11; s += d12; s += d13; s += d14;
  s += d15;

  Uh[p][c4] = s;
  __syncthreads();
  if (t < DIN / 4) {
    f4 r4 = (Uh[0][t] + Uh[1][t]) + (Uh[2][t] + Uh[3][t]);
    reinterpret_cast<f4*>(P + ((size_t)b * CHUNKS + chunk) * DIN)[t] = r4;
  }
}

// Kernel B (verbatim r9/r10): U[b] = sum_c P[b][c]; out = U * W.
// grid = B*8 blocks (64-wide k-tiles), 256 threads.
__global__ __launch_bounds__(256) void gemm_kernel(
    const float* __restrict__ P, const float* __restrict__ W,
    float* __restrict__ out) {
  const int b  = blockIdx.x >> 3;
  const int k0 = (blockIdx.x & 7) * 64;
  const int t  = threadIdx.x;

  __shared__ float  U[DIN];
  __shared__ f4     Uh[2][DIN / 4];
  __shared__ float  red[4][64];

  const f4* P4 = reinterpret_cast<const f4*>(P + (size_t)b * CHUNKS * DIN);
  const int col = t & 127, half = t >> 7;
  f4 s = (f4)(0.f);
  #pragma unroll
  for (int c = 0; c < CHUNKS / 2; ++c)
    s += P4[(size_t)(half * (CHUNKS / 2) + c) * (DIN / 4) + col];
  Uh[half][col] = s;
  __syncthreads();
  if (t < DIN / 4) {
    f4 a = Uh[0][t] + Uh[1][t];
    U[4 * t + 0] = a.x;
    U[4 * t + 1] = a.y;
    U[4 * t + 2] = a.z;
    U[4 * t + 3] = a.w;
  }
  __syncthreads();

  const int kk = t & 63;
  const int dg = t >> 6;
  const float* Wp = W + (size_t)(dg * 128) * K + k0 + kk;
  float acc = 0.f;
  #pragma unroll 16
  for (int d = 0; d < 128; ++d)
    acc += U[dg * 128 + d] * Wp[(size_t)d * K];   // U read = wave broadcast
  red[dg][kk] = acc;
  __syncthreads();

  if (t < 64)
    out[(size_t)b * K + k0 + t] =
        red[0][t] + red[1][t] + red[2][t] + red[3][t];
}

extern "C" void kernel_launch(void* const* d_in, const int* in_sizes, int n_in,
                              void* d_out, int out_size, void* d_ws, size_t ws_size,
                              hipStream_t stream) {
  const float* u = (const float*)d_in[0];   // [32,1024,512] f32
  const float* W = (const float*)d_in[1];   // [1,512,512]   f32
  float* out = (float*)d_out;               // [32,32,16]    f32
  float* P   = (float*)d_ws;                // [32][16][512] f32 = 1 MiB

  colsum_kernel<<<B * CHUNKS, 512, 0, stream>>>(u, P);
  gemm_kernel<<<B * 8, 256, 0, stream>>>(P, W, out);
}

// Round 12
// 19.267 us; speedup vs baseline: 6.4111x; 1.0387x over previous
//
#include <hip/hip_runtime.h>
#include <stdint.h>

// o[b,k] = sum_din (sum_i u[b,i,din]) * W[din,k]  (routing collapses; see r0).
// A (frozen, r11): sc1-nt asm loads, 512 thr x 512 blocks. ~4.5 TB/s cold-read
// wall (occupancy/streams/cache-bits all null -> per-CU in-flight-line limit).
// r12 experiment: B was latency-exposed (~8 serial HBM round-trips on cold W,
// 4 waves/CU). New B: W loads (32 independent f4/thread) hoisted ABOVE the
// stage-1 barrier -> W latency hides under P-read latency; stage 2 is pure
// VALU/LDS; 1 round-trip instead of 8.

typedef float f4 __attribute__((ext_vector_type(4)));

constexpr int B    = 32;
constexpr int I    = 1024;
constexpr int DIN  = 512;
constexpr int K    = 512;            // NUM_CAPSULE * DIM_CAPSULE
constexpr int CHUNKS = 16;           // 512 blocks, 128-KB slabs
constexpr int ROWS   = I / CHUNKS;   // 64 rows per chunk

// Kernel A: verbatim round-11.
__global__ __launch_bounds__(512) void colsum_kernel(
    const float* __restrict__ u, float* __restrict__ P) {
  const int b     = blockIdx.x >> 4;
  const int chunk = blockIdx.x & 15;
  const int t     = threadIdx.x;
  const int p     = t >> 7;
  const int c4    = t & 127;

  __shared__ f4 Uh[4][DIN / 4];

  const float* base =
      u + ((size_t)b * I + (size_t)chunk * ROWS + p) * DIN + 4 * (size_t)c4;
  uint64_t a  = (uint64_t)base;
  uint64_t st = 4ull * DIN * sizeof(float);

  f4 d0, d1, d2, d3, d4, d5, d6, d7, d8, d9, d10, d11, d12, d13, d14, d15;
  asm volatile(
      "global_load_dwordx4 %[d0],  %[a], off sc1 nt\n\t"
      "v_lshl_add_u64 %[a], %[st], 0, %[a]\n\t"
      "global_load_dwordx4 %[d1],  %[a], off sc1 nt\n\t"
      "v_lshl_add_u64 %[a], %[st], 0, %[a]\n\t"
      "global_load_dwordx4 %[d2],  %[a], off sc1 nt\n\t"
      "v_lshl_add_u64 %[a], %[st], 0, %[a]\n\t"
      "global_load_dwordx4 %[d3],  %[a], off sc1 nt\n\t"
      "v_lshl_add_u64 %[a], %[st], 0, %[a]\n\t"
      "global_load_dwordx4 %[d4],  %[a], off sc1 nt\n\t"
      "v_lshl_add_u64 %[a], %[st], 0, %[a]\n\t"
      "global_load_dwordx4 %[d5],  %[a], off sc1 nt\n\t"
      "v_lshl_add_u64 %[a], %[st], 0, %[a]\n\t"
      "global_load_dwordx4 %[d6],  %[a], off sc1 nt\n\t"
      "v_lshl_add_u64 %[a], %[st], 0, %[a]\n\t"
      "global_load_dwordx4 %[d7],  %[a], off sc1 nt\n\t"
      "v_lshl_add_u64 %[a], %[st], 0, %[a]\n\t"
      "global_load_dwordx4 %[d8],  %[a], off sc1 nt\n\t"
      "v_lshl_add_u64 %[a], %[st], 0, %[a]\n\t"
      "global_load_dwordx4 %[d9],  %[a], off sc1 nt\n\t"
      "v_lshl_add_u64 %[a], %[st], 0, %[a]\n\t"
      "global_load_dwordx4 %[d10], %[a], off sc1 nt\n\t"
      "v_lshl_add_u64 %[a], %[st], 0, %[a]\n\t"
      "global_load_dwordx4 %[d11], %[a], off sc1 nt\n\t"
      "v_lshl_add_u64 %[a], %[st], 0, %[a]\n\t"
      "global_load_dwordx4 %[d12], %[a], off sc1 nt\n\t"
      "v_lshl_add_u64 %[a], %[st], 0, %[a]\n\t"
      "global_load_dwordx4 %[d13], %[a], off sc1 nt\n\t"
      "v_lshl_add_u64 %[a], %[st], 0, %[a]\n\t"
      "global_load_dwordx4 %[d14], %[a], off sc1 nt\n\t"
      "v_lshl_add_u64 %[a], %[st], 0, %[a]\n\t"
      "global_load_dwordx4 %[d15], %[a], off sc1 nt\n\t"
      "s_waitcnt vmcnt(0)"
      : [d0] "=&v"(d0), [d1] "=&v"(d1), [d2] "=&v"(d2), [d3] "=&v"(d3),
        [d4] "=&v"(d4), [d5] "=&v"(d5), [d6] "=&v"(d6), [d7] "=&v"(d7),
        [d8] "=&v"(d8), [d9] "=&v"(d9), [d10] "=&v"(d10), [d11] "=&v"(d11),
        [d12] "=&v"(d12), [d13] "=&v"(d13), [d14] "=&v"(d14),
        [d15] "=&v"(d15), [a] "+v"(a)
      : [st] "v"(st)
      : "memory");

  f4 s = d0;
  s += d1;  s += d2;  s += d3;  s += d4;  s += d5;  s += d6;  s += d7;
  s += d8;  s += d9;  s += d10; s += d11; s += d12; s += d13; s += d14;
  s += d15;

  Uh[p][c4] = s;
  __syncthreads();
  if (t < DIN / 4) {
    f4 r4 = (Uh[0][t] + Uh[1][t]) + (Uh[2][t] + Uh[3][t]);
    reinterpret_cast<f4*>(P + ((size_t)b * CHUNKS + chunk) * DIN)[t] = r4;
  }
}

// Kernel B v2: W loads hoisted above stage-1 barrier (latency overlap);
// stage 2 pure VALU/LDS. grid = B*8 blocks (64-wide k-tiles), 256 threads.
__global__ __launch_bounds__(256) void gemm_kernel(
    const float* __restrict__ P, const float* __restrict__ W,
    float* __restrict__ out) {
  const int b  = blockIdx.x >> 3;
  const int k0 = (blockIdx.x & 7) * 64;
  const int t  = threadIdx.x;

  __shared__ float U[DIN];
  __shared__ f4    Uh[2][DIN / 4];
  __shared__ f4    red[16][16];

  // --- W prefetch: thread (dg, kc) owns 32 rows x one f4-col. 32 independent
  // loads, fully unrolled; they complete during stage-1's P-read wait. ---
  const int kc = t & 15;          // f4-col within 64-wide k-tile
  const int dg = t >> 4;          // d-group: rows [dg*32, dg*32+32)
  const f4* W4 = reinterpret_cast<const f4*>(W) + (size_t)(k0 >> 2) + kc;
  f4 w[32];
  #pragma unroll
  for (int d = 0; d < 32; ++d)
    w[d] = W4[(size_t)(dg * 32 + d) * (K / 4)];

  // --- Stage 1: U[b] = sum_c P[b][c] (8 f4 loads in flight/thread) ---
  const f4* P4 = reinterpret_cast<const f4*>(P + (size_t)b * CHUNKS * DIN);
  const int col = t & 127, half = t >> 7;
  f4 s = (f4)(0.f);
  #pragma unroll
  for (int c = 0; c < CHUNKS / 2; ++c)
    s += P4[(size_t)(half * (CHUNKS / 2) + c) * (DIN / 4) + col];
  Uh[half][col] = s;
  __syncthreads();
  if (t < DIN / 4) {
    f4 a = Uh[0][t] + Uh[1][t];
    U[4 * t + 0] = a.x;
    U[4 * t + 1] = a.y;
    U[4 * t + 2] = a.z;
    U[4 * t + 3] = a.w;
  }
  __syncthreads();

  // --- Stage 2: pure VALU — acc[kc] = sum_{d in dg} U[d] * w[d] ---
  f4 acc = (f4)(0.f);
  #pragma unroll
  for (int d = 0; d < 32; ++d)
    acc += U[dg * 32 + d] * w[d];     // U read = wave broadcast from LDS
  red[dg][kc] = acc;
  __syncthreads();

  // --- Cross-dg reduce: 64 threads, k = k0 + t ---
  if (t < 64) {
    const int c = t >> 2, comp = t & 3;
    float r = 0.f;
    #pragma unroll
    for (int g = 0; g < 16; ++g) r += red[g][c][comp];
    out[(size_t)b * K + k0 + t] = r;
  }
}

extern "C" void kernel_launch(void* const* d_in, const int* in_sizes, int n_in,
                              void* d_out, int out_size, void* d_ws, size_t ws_size,
                              hipStream_t stream) {
  const float* u = (const float*)d_in[0];   // [32,1024,512] f32
  const float* W = (const float*)d_in[1];   // [1,512,512]   f32
  float* out = (float*)d_out;               // [32,32,16]    f32
  float* P   = (float*)d_ws;                // [32][16][512] f32 = 1 MiB

  colsum_kernel<<<B * CHUNKS, 512, 0, stream>>>(u, P);
  gemm_kernel<<<B * 8, 256, 0, stream>>>(P, W, out);
}